// Round 1
// baseline (228.611 us; speedup 1.0000x reference)
//
#include <hip/hip_runtime.h>
#include <hip/hip_bf16.h>
#include <cstdint>
#include <cstddef>

#define B_ROWS 4096
#define D_DIM  256
#define TWOB   8192
#define K2     512            // hi|lo bf16 split → K doubled
static constexpr float kScale = 2.8853900817779268f; // log2(e)/TEMPERATURE, T=0.5

typedef __bf16 bf16_t;
typedef __bf16 bf16x8 __attribute__((ext_vector_type(8)));
typedef float  f32x4  __attribute__((ext_vector_type(4)));

// ---- workspace layout (all offsets 256B-aligned) ----
#define WS_Z2   0ull                                  // bf16 [8192][512], group-swizzled
#define WS_Z32  (WS_Z2  + (size_t)TWOB * K2 * 2)      // f32  [8192][256]
#define WS_KEYS (WS_Z32 + (size_t)TWOB * D_DIM * 4)   // i32  [8192]
#define WS_DEN  (WS_KEYS + (size_t)TWOB * 4)          // f32  [8192]
#define WS_ACC  (WS_DEN + (size_t)TWOB * 4)           // f32  [2]  (S1 = sum log denom, S2 = sum pair dots)

// Swizzle: within each 64-element K-chunk (128 B), permute the 8 16B-groups by
// XOR with (row&7). Stored this way in GLOBAL memory so that linear
// global_load_lds staging lands pre-swizzled in LDS (m173 pattern), and
// ds_read_b128 fragment reads are bank-conflict-free.
__device__ __forceinline__ int swz_k(int r, int k) {
  int chunk = k >> 6, kc = k & 63;
  int g = kc >> 3;
  return chunk * 64 + (((g ^ (r & 7)) << 3)) + (kc & 7);
}

// ---------------- kernel 1: normalize + bf16 hi/lo split + keys + zero accum ----------------
__global__ __launch_bounds__(256) void prep_kernel(
    const float* __restrict__ emb_i, const float* __restrict__ emb_j,
    const int* __restrict__ tags, const int* __restrict__ docs,
    bf16_t* __restrict__ Z2s, float* __restrict__ z32,
    int* __restrict__ keys, float* __restrict__ denom, float* __restrict__ accums)
{
  const int r = blockIdx.x;
  const int t = threadIdx.x;
  const int lane = t & 63, w = t >> 6;
  const float* src = (r < B_ROWS) ? (emb_i + (size_t)r * D_DIM)
                                  : (emb_j + (size_t)(r - B_ROWS) * D_DIM);
  float v = src[t];
  float ss = v * v;
  #pragma unroll
  for (int m = 32; m; m >>= 1) ss += __shfl_xor(ss, m, 64);
  __shared__ float red[4];
  if (lane == 0) red[w] = ss;
  __syncthreads();
  float tot = red[0] + red[1] + red[2] + red[3];
  float z = v / sqrtf(tot);
  z32[(size_t)r * D_DIM + t] = z;
  bf16_t hi = (bf16_t)z;
  float hif = (float)hi;
  bf16_t lo = (bf16_t)(z - hif);
  Z2s[(size_t)r * K2 + swz_k(r, t)]       = hi;
  Z2s[(size_t)r * K2 + swz_k(r, t + 256)] = lo;
  if (t == 0) {
    int rb = (r < B_ROWS) ? r : (r - B_ROWS);
    keys[r] = (tags[rb] << 16) | docs[rb];   // tag<100 (7b) | doc<512 (9b): disjoint halves
    denom[r] = 0.f;
  }
  if (r == 0 && t < 2) accums[t] = 0.f;
}

// ---------------- kernel 2: fused sim-GEMM + exp + mask + row-sum ----------------
#define BM  128
#define BK  64
#define NCT 8     // col tiles per block → strip of 1024 columns

__global__ __launch_bounds__(256, 2) void fused_kernel(
    const bf16_t* __restrict__ Z2s, const int* __restrict__ keys,
    float* __restrict__ denom)
{
  __shared__ bf16_t sB[2][BM * BK];   // 2 x 16 KB double buffer, B-panel only
  const int tid  = threadIdx.x;
  const int lane = tid & 63;
  const int w    = tid >> 6;
  const int wr = w >> 1, wc = w & 1;          // 2x2 waves, each 64x64 output
  const int rt = blockIdx.x;                   // row tile (64 of them)
  const int s  = blockIdx.y;                   // col strip (8 of them)
  const int row0 = rt * BM;
  const int c00  = s * (NCT * 128);
  const int l15 = lane & 15, l4 = lane >> 4;

  // keys for my 16 output rows
  int keyr[4][4];
  #pragma unroll
  for (int mi = 0; mi < 4; ++mi)
    #pragma unroll
    for (int j = 0; j < 4; ++j)
      keyr[mi][j] = keys[row0 + wr * 64 + mi * 16 + l4 * 4 + j];

  // A fragments for the FULL K=512 kept in registers (64 VGPR/lane),
  // loaded once per block straight from (pre-swizzled) global.
  bf16x8 afrag[4][16];
  #pragma unroll
  for (int mi = 0; mi < 4; ++mi) {
    int row = row0 + wr * 64 + mi * 16 + l15;
    const bf16_t* rowp = Z2s + (size_t)row * K2;
    #pragma unroll
    for (int kk = 0; kk < 16; ++kk) {
      int g  = (kk & 1) * 4 + l4;
      int gs = g ^ (row & 7);
      afrag[mi][kk] = *(const bf16x8*)(rowp + (kk >> 1) * 64 + gs * 8);
    }
  }

  float rowsum[4][4];
  #pragma unroll
  for (int mi = 0; mi < 4; ++mi)
    #pragma unroll
    for (int j = 0; j < 4; ++j) rowsum[mi][j] = 0.f;

  for (int ct = 0; ct < NCT; ++ct) {
    const int cbase = c00 + ct * 128;

    f32x4 acc[4][4];
    const f32x4 vzero = {0.f, 0.f, 0.f, 0.f};
    #pragma unroll
    for (int mi = 0; mi < 4; ++mi)
      #pragma unroll
      for (int ni = 0; ni < 4; ++ni) acc[mi][ni] = vzero;

    // stage kt=0 into buf 0 (16 KB = 256 thr x 4 x 16B, linear dest)
    #pragma unroll
    for (int i = 0; i < 4; ++i) {
      int o = i * 4096 + tid * 16;
      int r_l = o >> 7, ob = o & 127;
      const bf16_t* g = Z2s + (size_t)(cbase + r_l) * K2 + (ob >> 1);
      __builtin_amdgcn_global_load_lds(
          (const __attribute__((address_space(1))) void*)g,
          (__attribute__((address_space(3))) void*)((char*)&sB[0][0] + o),
          16, 0, 0);
    }

    #pragma unroll
    for (int kt = 0; kt < 8; ++kt) {
      const int buf = kt & 1;
      __syncthreads();                       // compiler drains vmcnt before barrier
      if (kt < 7) {
        #pragma unroll
        for (int i = 0; i < 4; ++i) {
          int o = i * 4096 + tid * 16;
          int r_l = o >> 7, ob = o & 127;
          const bf16_t* g = Z2s + (size_t)(cbase + r_l) * K2 + (kt + 1) * 64 + (ob >> 1);
          __builtin_amdgcn_global_load_lds(
              (const __attribute__((address_space(1))) void*)g,
              (__attribute__((address_space(3))) void*)((char*)&sB[buf ^ 1][0] + o),
              16, 0, 0);
        }
      }
      // B fragment reads (swizzled) then 32 MFMAs against register-resident A
      const bf16_t* bb = &sB[buf][0];
      bf16x8 bfr[2][4];
      #pragma unroll
      for (int half = 0; half < 2; ++half)
        #pragma unroll
        for (int ni = 0; ni < 4; ++ni) {
          int c_l = wc * 64 + ni * 16 + l15;
          int g   = half * 4 + l4;
          int gs  = g ^ (c_l & 7);
          bfr[half][ni] = *(const bf16x8*)(bb + c_l * 64 + gs * 8);
        }
      #pragma unroll
      for (int half = 0; half < 2; ++half)
        #pragma unroll
        for (int mi = 0; mi < 4; ++mi)
          #pragma unroll
          for (int ni = 0; ni < 4; ++ni)
            acc[mi][ni] = __builtin_amdgcn_mfma_f32_16x16x32_bf16(
                afrag[mi][kt * 2 + half], bfr[half][ni], acc[mi][ni], 0, 0, 0);
      __syncthreads();
    }

    // epilogue: exp + mask + row-accumulate (overlaps next ct's staging latency)
    #pragma unroll
    for (int ni = 0; ni < 4; ++ni) {
      int col  = cbase + wc * 64 + ni * 16 + l15;
      int keyc = keys[col];
      #pragma unroll
      for (int mi = 0; mi < 4; ++mi) {
        #pragma unroll
        for (int j = 0; j < 4; ++j) {
          int x = keyr[mi][j] ^ keyc;
          bool m = ((x >> 16) != 0) & ((x & 0xFFFF) != 0);  // tag differs AND doc differs
          float e = __builtin_amdgcn_exp2f(acc[mi][ni][j] * kScale);
          rowsum[mi][j] += m ? e : 0.f;
        }
      }
    }
  }

  // reduce across the 16 columns held by lanes (l&15), one atomic per row
  #pragma unroll
  for (int mi = 0; mi < 4; ++mi)
    #pragma unroll
    for (int j = 0; j < 4; ++j) {
      float v = rowsum[mi][j];
      v += __shfl_xor(v, 1, 64);
      v += __shfl_xor(v, 2, 64);
      v += __shfl_xor(v, 4, 64);
      v += __shfl_xor(v, 8, 64);
      if (l15 == 0)
        atomicAdd(&denom[row0 + wr * 64 + mi * 16 + l4 * 4 + j], v);
    }
}

// ---------------- kernel 3: S1 = sum log(denom+0.1), S2 = sum_r dot(z_i[r], z_j[r]) ----------------
__global__ __launch_bounds__(256) void reduce_kernel(
    const float* __restrict__ denom, const float* __restrict__ z32,
    float* __restrict__ accums)
{
  const int t = threadIdx.x;
  const int lane = t & 63, w = t >> 6;
  const int gtid = blockIdx.x * 256 + t;

  float s1 = 0.f;
  if (gtid < TWOB) s1 = __logf(denom[gtid] + 0.1f);
  #pragma unroll
  for (int m = 32; m; m >>= 1) s1 += __shfl_xor(s1, m, 64);

  float s2 = 0.f;
  int gw = blockIdx.x * 4 + w;           // 128 blocks * 4 waves = 512 waves
  for (int r = gw; r < B_ROWS; r += 512) {
    const float* zi = z32 + (size_t)r * D_DIM;
    const float* zj = z32 + (size_t)(r + B_ROWS) * D_DIM;
    float d = 0.f;
    #pragma unroll
    for (int i = 0; i < 4; ++i) d = fmaf(zi[lane + 64 * i], zj[lane + 64 * i], d);
    #pragma unroll
    for (int m = 32; m; m >>= 1) d += __shfl_xor(d, m, 64);
    s2 += d;                              // replicated across lanes; lane0's copy used
  }

  __shared__ float red1[4], red2[4];
  if (lane == 0) { red1[w] = s1; red2[w] = s2; }
  __syncthreads();
  if (t == 0) {
    atomicAdd(&accums[0], red1[0] + red1[1] + red1[2] + red1[3]);
    atomicAdd(&accums[1], red2[0] + red2[1] + red2[2] + red2[3]);
  }
}

// ---------------- kernel 4: loss = (S1 - 2*S2/T) / (2B),  2/T = 4 ----------------
__global__ void finish_kernel(const float* __restrict__ accums, float* __restrict__ out)
{
  if (threadIdx.x == 0)
    out[0] = (accums[0] - 4.0f * accums[1]) * (1.0f / (float)TWOB);
}

extern "C" void kernel_launch(void* const* d_in, const int* in_sizes, int n_in,
                              void* d_out, int out_size, void* d_ws, size_t ws_size,
                              hipStream_t stream) {
  const float* emb_i = (const float*)d_in[0];
  const float* emb_j = (const float*)d_in[1];
  const int*   tags  = (const int*)d_in[2];
  // d_in[3] = num_classes (unused)
  const int*   docs  = (const int*)d_in[4];

  char* ws = (char*)d_ws;
  bf16_t* Z2s   = (bf16_t*)(ws + WS_Z2);
  float*  z32   = (float*)(ws + WS_Z32);
  int*    keys  = (int*)(ws + WS_KEYS);
  float*  denom = (float*)(ws + WS_DEN);
  float*  accums= (float*)(ws + WS_ACC);
  float*  out   = (float*)d_out;

  prep_kernel<<<TWOB, 256, 0, stream>>>(emb_i, emb_j, tags, docs, Z2s, z32, keys, denom, accums);
  fused_kernel<<<dim3(TWOB / BM, TWOB / (NCT * 128)), 256, 0, stream>>>(Z2s, keys, denom);
  reduce_kernel<<<128, 256, 0, stream>>>(denom, z32, accums);
  finish_kernel<<<1, 64, 0, stream>>>(accums, out);
}

// Round 3
// 133.749 us; speedup vs baseline: 1.7093x; 1.7093x over previous
//
#include <hip/hip_runtime.h>
#include <hip/hip_bf16.h>
#include <cstdint>
#include <cstddef>

#define B_ROWS 4096
#define D_DIM  256
#define TWOB   8192
static constexpr float kScale = 2.8853900817779268f; // log2(e)/TEMPERATURE, T=0.5

typedef __bf16 bf16_t;
typedef __bf16 bf16x4 __attribute__((ext_vector_type(4)));
typedef __bf16 bf16x8 __attribute__((ext_vector_type(8)));
typedef float  f32x4  __attribute__((ext_vector_type(4)));

// ---- workspace layout ----
#define WS_Z    0ull                                  // bf16 [8192][256], group-swizzled per row
#define WS_KEYS ((size_t)TWOB * D_DIM * 2)            // i32 [8192]
#define WS_DEN  (WS_KEYS + (size_t)TWOB * 4)          // f32 [8192]
#define WS_ACC  (WS_DEN + (size_t)TWOB * 4)           // f32 [2]

// Swizzle: within each 64-elem K-chunk (128 B), the 8 16B-groups are permuted
// by XOR with (row&7), baked into the GLOBAL layout so linear global_load_lds
// staging lands pre-swizzled in LDS (m173 pattern) and ds_read_b128 fragment
// reads are bank-conflict-free. Rows r and r+4096 share (r&7) → identical
// permutation, so elementwise pair-dots over the stored layout are correct.

// ---------------- kernel 1: normalize + bf16 + swizzled store + keys + zero accum ----------------
__global__ __launch_bounds__(256) void prep_kernel(
    const float* __restrict__ emb_i, const float* __restrict__ emb_j,
    const int* __restrict__ tags, const int* __restrict__ docs,
    bf16_t* __restrict__ Z, int* __restrict__ keys,
    float* __restrict__ denom, float* __restrict__ accums)
{
  const int t = threadIdx.x;
  const int lane = t & 63, w = t >> 6;
  const int row = blockIdx.x * 4 + w;           // one row per wave
  const float* src = (row < B_ROWS) ? (emb_i + (size_t)row * D_DIM)
                                    : (emb_j + (size_t)(row - B_ROWS) * D_DIM);
  float4 v = *(const float4*)(src + lane * 4);
  float ss = v.x * v.x + v.y * v.y + v.z * v.z + v.w * v.w;
  #pragma unroll
  for (int m = 32; m; m >>= 1) ss += __shfl_xor(ss, m, 64);
  float inv = 1.0f / sqrtf(ss);

  bf16x4 q;
  q[0] = (bf16_t)(v.x * inv);
  q[1] = (bf16_t)(v.y * inv);
  q[2] = (bf16_t)(v.z * inv);
  q[3] = (bf16_t)(v.w * inv);

  // lane l holds elements k = 4l..4l+3 → chunk = l>>4, group g = (l>>1)&7, half = l&1
  int chunk = lane >> 4;
  int g     = (lane >> 1) & 7;
  int gs    = g ^ (row & 7);
  int half  = lane & 1;
  *(bf16x4*)(Z + (size_t)row * D_DIM + chunk * 64 + gs * 8 + half * 4) = q;

  if (lane == 0) {
    int rb = (row < B_ROWS) ? row : (row - B_ROWS);
    keys[row] = (tags[rb] << 16) | docs[rb];    // tag<100 (7b) | doc<512 (9b)
    denom[row] = 0.f;
  }
  if (blockIdx.x == 0 && t < 2) accums[t] = 0.f;
}

// ---------------- kernel 2: triangular fused sim-GEMM + exp + mask + row/col sums ----------------
#define BM 128
#define BK 64
#define NKT (D_DIM / BK)   // 4 K-steps

__global__ __launch_bounds__(256, 2) void fused_kernel(
    const bf16_t* __restrict__ Z, const int* __restrict__ keys,
    float* __restrict__ denom)
{
  __shared__ bf16_t sA[2][BM * BK];   // 2 x 16 KB
  __shared__ bf16_t sB[2][BM * BK];   // 2 x 16 KB
  const int tid  = threadIdx.x;
  const int lane = tid & 63;
  const int w    = tid >> 6;
  const int wr = w >> 1, wc = w & 1;           // 2x2 waves, each 64x64 output
  const int l15 = lane & 15, l4 = lane >> 4;

  // triangular decode: bid -> (rt, ct), rt >= ct
  int bid = blockIdx.x;
  int rt = (int)((sqrtf(8.0f * (float)bid + 1.0f) - 1.0f) * 0.5f);
  while ((rt + 1) * (rt + 2) / 2 <= bid) ++rt;
  while (rt * (rt + 1) / 2 > bid) --rt;
  const int ct = bid - rt * (rt + 1) / 2;
  const int row0 = rt * BM, col0 = ct * BM;
  const bool offdiag = (rt != ct);

  f32x4 acc[4][4];
  const f32x4 vzero = {0.f, 0.f, 0.f, 0.f};
  #pragma unroll
  for (int mi = 0; mi < 4; ++mi)
    #pragma unroll
    for (int ni = 0; ni < 4; ++ni) acc[mi][ni] = vzero;

  // stage both 128x64 tiles for K-step kt into buf (linear dest, 4x16B per thread per tile)
  auto STAGE = [&](int buf, int kt) {
    #pragma unroll
    for (int i = 0; i < 4; ++i) {
      int o  = i * 4096 + tid * 16;            // byte offset within 16KB tile
      int rl = o >> 7, ob = o & 127;
      const bf16_t* ga = Z + (size_t)(row0 + rl) * D_DIM + kt * 64 + (ob >> 1);
      __builtin_amdgcn_global_load_lds(
          (const __attribute__((address_space(1))) void*)ga,
          (__attribute__((address_space(3))) void*)((char*)&sA[buf][0] + o), 16, 0, 0);
      const bf16_t* gb = Z + (size_t)(col0 + rl) * D_DIM + kt * 64 + (ob >> 1);
      __builtin_amdgcn_global_load_lds(
          (const __attribute__((address_space(1))) void*)gb,
          (__attribute__((address_space(3))) void*)((char*)&sB[buf][0] + o), 16, 0, 0);
    }
  };

  STAGE(0, 0);
  #pragma unroll
  for (int kt = 0; kt < NKT; ++kt) {
    const int buf = kt & 1;
    __syncthreads();                            // drains vmcnt → staged tile ready
    if (kt < NKT - 1) STAGE(buf ^ 1, kt + 1);

    bf16x8 af[2][4], bfr[2][4];
    #pragma unroll
    for (int h = 0; h < 2; ++h) {
      #pragma unroll
      for (int mi = 0; mi < 4; ++mi) {
        int rl  = wr * 64 + mi * 16 + l15;
        int gsa = (h * 4 + l4) ^ (rl & 7);
        af[h][mi] = *(const bf16x8*)(&sA[buf][rl * 64 + gsa * 8]);
        int cl  = wc * 64 + mi * 16 + l15;
        int gsb = (h * 4 + l4) ^ (cl & 7);
        bfr[h][mi] = *(const bf16x8*)(&sB[buf][cl * 64 + gsb * 8]);
      }
    }
    #pragma unroll
    for (int h = 0; h < 2; ++h)
      #pragma unroll
      for (int mi = 0; mi < 4; ++mi)
        #pragma unroll
        for (int ni = 0; ni < 4; ++ni)
          acc[mi][ni] = __builtin_amdgcn_mfma_f32_16x16x32_bf16(
              af[h][mi], bfr[h][ni], acc[mi][ni], 0, 0, 0);
    __syncthreads();
  }

  // ---- epilogue: exp + mask; rowsum for tile rows, colsum (symmetry) for tile cols ----
  int keyr[4][4];
  #pragma unroll
  for (int mi = 0; mi < 4; ++mi)
    #pragma unroll
    for (int j = 0; j < 4; ++j)
      keyr[mi][j] = keys[row0 + wr * 64 + mi * 16 + l4 * 4 + j];
  int keyc[4];
  #pragma unroll
  for (int ni = 0; ni < 4; ++ni)
    keyc[ni] = keys[col0 + wc * 64 + ni * 16 + l15];

  float rowsum[4][4];
  #pragma unroll
  for (int mi = 0; mi < 4; ++mi)
    #pragma unroll
    for (int j = 0; j < 4; ++j) rowsum[mi][j] = 0.f;
  float colsum[4] = {0.f, 0.f, 0.f, 0.f};

  #pragma unroll
  for (int ni = 0; ni < 4; ++ni) {
    #pragma unroll
    for (int mi = 0; mi < 4; ++mi) {
      #pragma unroll
      for (int j = 0; j < 4; ++j) {
        int x = keyr[mi][j] ^ keyc[ni];
        bool m = ((x >> 16) != 0) & ((x & 0xFFFF) != 0);  // tag differs AND doc differs
        float e = m ? __builtin_amdgcn_exp2f(acc[mi][ni][j] * kScale) : 0.f;
        rowsum[mi][j] += e;
        colsum[ni] += e;
      }
    }
  }

  // rowsum: reduce over the 16 column-lanes (l15), one atomic per row
  #pragma unroll
  for (int mi = 0; mi < 4; ++mi)
    #pragma unroll
    for (int j = 0; j < 4; ++j) {
      float v = rowsum[mi][j];
      v += __shfl_xor(v, 1, 64);
      v += __shfl_xor(v, 2, 64);
      v += __shfl_xor(v, 4, 64);
      v += __shfl_xor(v, 8, 64);
      if (l15 == 0)
        atomicAdd(&denom[row0 + wr * 64 + mi * 16 + l4 * 4 + j], v);
    }
  // colsum: reduce over row-lanes (l4) — symmetric contribution, off-diag tiles only
  if (offdiag) {
    #pragma unroll
    for (int ni = 0; ni < 4; ++ni) {
      float v = colsum[ni];
      v += __shfl_xor(v, 16, 64);
      v += __shfl_xor(v, 32, 64);
      if (l4 == 0)
        atomicAdd(&denom[col0 + wc * 64 + ni * 16 + l15], v);
    }
  }
}

// ---------------- kernel 3: S1 = Σ log(denom+0.1), S2 = Σ_r dot(z_i[r], z_j[r]) ----------------
__global__ __launch_bounds__(256) void reduce_kernel(
    const float* __restrict__ denom, const bf16_t* __restrict__ Z,
    float* __restrict__ accums)
{
  const int t = threadIdx.x;
  const int lane = t & 63, w = t >> 6;
  const int g = blockIdx.x * 256 + t;

  float s1 = (g < TWOB) ? __logf(denom[g] + 0.1f) : 0.f;

  float s2 = 0.f;
  int gw = blockIdx.x * 4 + w;                  // 128 waves total
  for (int r = gw; r < B_ROWS; r += 128) {
    bf16x4 a = *(const bf16x4*)(Z + (size_t)r * D_DIM + lane * 4);
    bf16x4 b = *(const bf16x4*)(Z + (size_t)(r + B_ROWS) * D_DIM + lane * 4);
    float d = 0.f;
    #pragma unroll
    for (int i = 0; i < 4; ++i) d = fmaf((float)a[i], (float)b[i], d);
    s2 += d;                                    // per-lane partial; reduced once below
  }

  #pragma unroll
  for (int m = 32; m; m >>= 1) {
    s1 += __shfl_xor(s1, m, 64);
    s2 += __shfl_xor(s2, m, 64);
  }
  __shared__ float r1[4], r2[4];
  if (lane == 0) { r1[w] = s1; r2[w] = s2; }
  __syncthreads();
  if (t == 0) {
    atomicAdd(&accums[0], r1[0] + r1[1] + r1[2] + r1[3]);
    atomicAdd(&accums[1], r2[0] + r2[1] + r2[2] + r2[3]);
  }
}

// ---------------- kernel 4: loss = (S1 - 4*S2) / 2B ----------------
__global__ void finish_kernel(const float* __restrict__ accums, float* __restrict__ out)
{
  if (threadIdx.x == 0)
    out[0] = (accums[0] - 4.0f * accums[1]) * (1.0f / (float)TWOB);
}

extern "C" void kernel_launch(void* const* d_in, const int* in_sizes, int n_in,
                              void* d_out, int out_size, void* d_ws, size_t ws_size,
                              hipStream_t stream) {
  const float* emb_i = (const float*)d_in[0];
  const float* emb_j = (const float*)d_in[1];
  const int*   tags  = (const int*)d_in[2];
  // d_in[3] = num_classes (unused)
  const int*   docs  = (const int*)d_in[4];

  char* ws = (char*)d_ws;
  bf16_t* Z      = (bf16_t*)(ws + WS_Z);
  int*    keys   = (int*)(ws + WS_KEYS);
  float*  denom  = (float*)(ws + WS_DEN);
  float*  accums = (float*)(ws + WS_ACC);
  float*  out    = (float*)d_out;

  prep_kernel<<<TWOB / 4, 256, 0, stream>>>(emb_i, emb_j, tags, docs, Z, keys, denom, accums);
  const int ntiles = (TWOB / BM) * (TWOB / BM + 1) / 2;   // 64*65/2 = 2080 lower-tri tiles
  fused_kernel<<<ntiles, 256, 0, stream>>>(Z, keys, denom);
  reduce_kernel<<<TWOB / 256, 256, 0, stream>>>(denom, Z, accums);
  finish_kernel<<<1, 64, 0, stream>>>(accums, out);
}

// Round 5
// 122.657 us; speedup vs baseline: 1.8638x; 1.0904x over previous
//
#include <hip/hip_runtime.h>
#include <hip/hip_bf16.h>
#include <cstdint>
#include <cstddef>

#define B_ROWS 4096
#define D_DIM  256
#define TWOB   8192
static constexpr float kScale = 2.8853900817779268f; // log2(e)/TEMPERATURE, T=0.5

typedef __bf16 bf16_t;
typedef __bf16 bf16x4 __attribute__((ext_vector_type(4)));
typedef __bf16 bf16x8 __attribute__((ext_vector_type(8)));
typedef float  f32x4  __attribute__((ext_vector_type(4)));

// ---- workspace layout ----
#define WS_Z    0ull                                  // bf16 [8192][256], group-swizzled per row
#define WS_KEYS ((size_t)TWOB * D_DIM * 2)            // i32 [8192]
#define WS_DEN  (WS_KEYS + (size_t)TWOB * 4)          // f32 [8192]
#define WS_PAIR (WS_DEN + (size_t)TWOB * 4)           // f32 [4096] per-pair dots (fp32 z)

// Swizzle: within each 64-elem K-chunk (128 B), the 8 16B-groups are permuted
// by XOR with (row&7), baked into the GLOBAL layout so linear global_load_lds
// staging lands pre-swizzled in LDS (m173 pattern) and ds_read_b128 fragment
// reads are bank-conflict-free (verified: SQ_LDS_BANK_CONFLICT == 0).

// ---------------- kernel 1: normalize + bf16 swizzled store + keys + denom-zero + pair dots ----------------
__global__ __launch_bounds__(256) void prep_kernel(
    const float* __restrict__ emb_i, const float* __restrict__ emb_j,
    const int* __restrict__ tags, const int* __restrict__ docs,
    bf16_t* __restrict__ Z, int* __restrict__ keys,
    float* __restrict__ denom, float* __restrict__ pair)
{
  __shared__ float4 zbuf[4][64];
  const int t = threadIdx.x;
  const int lane = t & 63, w = t >> 6;
  const int b = blockIdx.x;                     // 2048 blocks
  // wave 0 -> row 2b (emb_i), wave 1 -> 2b+1 (emb_i), wave 2 -> 2b+4096, wave 3 -> 2b+1+4096
  const int rlocal = 2 * b + (w & 1);
  const int row = rlocal + (w >> 1) * B_ROWS;
  const float* src = (w >> 1) ? (emb_j + (size_t)rlocal * D_DIM)
                              : (emb_i + (size_t)rlocal * D_DIM);
  float4 v = *(const float4*)(src + lane * 4);
  float ss = v.x * v.x + v.y * v.y + v.z * v.z + v.w * v.w;
  #pragma unroll
  for (int m = 32; m; m >>= 1) ss += __shfl_xor(ss, m, 64);
  float inv = 1.0f / sqrtf(ss);
  float4 z = {v.x * inv, v.y * inv, v.z * inv, v.w * inv};
  zbuf[w][lane] = z;

  bf16x4 q;
  q[0] = (bf16_t)z.x; q[1] = (bf16_t)z.y; q[2] = (bf16_t)z.z; q[3] = (bf16_t)z.w;
  // lane l holds elems k=4l..4l+3 -> chunk=l>>4, group g=(l>>1)&7, half=l&1
  int chunk = lane >> 4;
  int g     = (lane >> 1) & 7;
  int gs    = g ^ (row & 7);
  int half  = lane & 1;
  *(bf16x4*)(Z + (size_t)row * D_DIM + chunk * 64 + gs * 8 + half * 4) = q;

  if (lane == 0) {
    keys[row] = (tags[rlocal] << 16) | docs[rlocal];  // tag<100 (7b) | doc<512 (9b)
    denom[row] = 0.f;
  }
  __syncthreads();
  if (w < 2) {  // pair dot from fp32 z (pre-rounding): rows (2b+w) and (2b+w)+4096
    float4 a = zbuf[w][lane], c = zbuf[w + 2][lane];
    float d = a.x * c.x + a.y * c.y + a.z * c.z + a.w * c.w;
    #pragma unroll
    for (int m = 32; m; m >>= 1) d += __shfl_xor(d, m, 64);
    if (lane == 0) pair[2 * b + w] = d;
  }
}

// ---------------- kernel 2: triangular fused sim-GEMM + exp + mask + row/col sums ----------------
#define BM 128
#define BK 64
#define NKT (D_DIM / BK)   // 4 K-steps per tile
#define STRIP 2            // tiles per block; 2080/2 = 1040 blocks

__global__ __launch_bounds__(256, 2) void fused_kernel(
    const bf16_t* __restrict__ Z, const int* __restrict__ keys,
    float* __restrict__ denom)
{
  __shared__ bf16_t sA[2][BM * BK];   // 2 x 16 KB
  __shared__ bf16_t sB[2][BM * BK];   // 2 x 16 KB
  const int tid  = threadIdx.x;
  const int lane = tid & 63;
  const int w    = tid >> 6;
  const int wr = w >> 1, wc = w & 1;           // 2x2 waves, each 64x64 output
  const int l15 = lane & 15, l4 = lane >> 4;

  // decode tile t0 = 2*bid, then t1 = t0+1 (next in triangle order)
  int t0 = 2 * blockIdx.x;
  int rt0 = (int)((sqrtf(8.0f * (float)t0 + 1.0f) - 1.0f) * 0.5f);
  while ((rt0 + 1) * (rt0 + 2) / 2 <= t0) ++rt0;
  while (rt0 * (rt0 + 1) / 2 > t0) --rt0;
  int ct0 = t0 - rt0 * (rt0 + 1) / 2;
  int rt1 = (ct0 < rt0) ? rt0 : rt0 + 1;
  int ct1 = (ct0 < rt0) ? ct0 + 1 : 0;

  const int  r0s[2] = {rt0 * BM, rt1 * BM};
  const int  c0s[2] = {ct0 * BM, ct1 * BM};
  const bool od[2]  = {rt0 != ct0, rt1 != ct1};

  f32x4 acc[4][4];
  const f32x4 vzero = {0.f, 0.f, 0.f, 0.f};
  #pragma unroll
  for (int mi = 0; mi < 4; ++mi)
    #pragma unroll
    for (int ni = 0; ni < 4; ++ni) acc[mi][ni] = vzero;

  // stage both 128x64 tiles of (tile ti, K-step kt) into buf (linear dest)
  auto STAGE = [&](int buf, int ti, int kt) {
    #pragma unroll
    for (int i = 0; i < 4; ++i) {
      int o  = i * 4096 + tid * 16;            // byte offset within 16KB tile
      int rl = o >> 7, ob = o & 127;
      const bf16_t* ga = Z + (size_t)(r0s[ti] + rl) * D_DIM + kt * 64 + (ob >> 1);
      __builtin_amdgcn_global_load_lds(
          (const __attribute__((address_space(1))) void*)ga,
          (__attribute__((address_space(3))) void*)((char*)&sA[buf][0] + o), 16, 0, 0);
      const bf16_t* gb = Z + (size_t)(c0s[ti] + rl) * D_DIM + kt * 64 + (ob >> 1);
      __builtin_amdgcn_global_load_lds(
          (const __attribute__((address_space(1))) void*)gb,
          (__attribute__((address_space(3))) void*)((char*)&sB[buf][0] + o), 16, 0, 0);
    }
  };

  // epilogue for tile ti: exp + mask; rowsum (atomic) + colsum (atomic, symmetry)
  auto EPI = [&](int ti) {
    const int row0 = r0s[ti], col0 = c0s[ti];
    int keyr[4][4];
    #pragma unroll
    for (int mi = 0; mi < 4; ++mi)
      #pragma unroll
      for (int j = 0; j < 4; ++j)
        keyr[mi][j] = keys[row0 + wr * 64 + mi * 16 + l4 * 4 + j];
    int keyc[4];
    #pragma unroll
    for (int ni = 0; ni < 4; ++ni)
      keyc[ni] = keys[col0 + wc * 64 + ni * 16 + l15];

    float rowsum[4][4];
    #pragma unroll
    for (int mi = 0; mi < 4; ++mi)
      #pragma unroll
      for (int j = 0; j < 4; ++j) rowsum[mi][j] = 0.f;
    float colsum[4] = {0.f, 0.f, 0.f, 0.f};

    #pragma unroll
    for (int ni = 0; ni < 4; ++ni) {
      #pragma unroll
      for (int mi = 0; mi < 4; ++mi) {
        #pragma unroll
        for (int j = 0; j < 4; ++j) {
          int x = keyr[mi][j] ^ keyc[ni];
          bool m = ((x >> 16) != 0) & ((x & 0xFFFF) != 0);  // tag differs AND doc differs
          float e = m ? __builtin_amdgcn_exp2f(acc[mi][ni][j] * kScale) : 0.f;
          rowsum[mi][j] += e;
          colsum[ni] += e;
        }
      }
    }
    #pragma unroll
    for (int mi = 0; mi < 4; ++mi)
      #pragma unroll
      for (int j = 0; j < 4; ++j) {
        float v = rowsum[mi][j];
        v += __shfl_xor(v, 1, 64);
        v += __shfl_xor(v, 2, 64);
        v += __shfl_xor(v, 4, 64);
        v += __shfl_xor(v, 8, 64);
        if (l15 == 0)
          atomicAdd(&denom[row0 + wr * 64 + mi * 16 + l4 * 4 + j], v);
      }
    if (od[ti]) {
      #pragma unroll
      for (int ni = 0; ni < 4; ++ni) {
        float v = colsum[ni];
        v += __shfl_xor(v, 16, 64);
        v += __shfl_xor(v, 32, 64);
        if (l4 == 0)
          atomicAdd(&denom[col0 + wc * 64 + ni * 16 + l15], v);
      }
    }
    // reset accumulator for the next tile
    #pragma unroll
    for (int mi = 0; mi < 4; ++mi)
      #pragma unroll
      for (int ni = 0; ni < 4; ++ni) acc[mi][ni] = vzero;
  };

  STAGE(0, 0, 0);
  #pragma unroll
  for (int s = 0; s < STRIP * NKT; ++s) {       // 8 seamless dbuf K-steps
    const int buf = s & 1;
    __syncthreads();                            // staged tile for step s ready
    if (s < STRIP * NKT - 1) STAGE(buf ^ 1, (s + 1) >> 2, (s + 1) & 3);

    bf16x8 af[2][4], bfr[2][4];
    #pragma unroll
    for (int h = 0; h < 2; ++h) {
      #pragma unroll
      for (int mi = 0; mi < 4; ++mi) {
        int rl  = wr * 64 + mi * 16 + l15;
        int gsa = (h * 4 + l4) ^ (rl & 7);
        af[h][mi] = *(const bf16x8*)(&sA[buf][rl * 64 + gsa * 8]);
        int cl  = wc * 64 + mi * 16 + l15;
        int gsb = (h * 4 + l4) ^ (cl & 7);
        bfr[h][mi] = *(const bf16x8*)(&sB[buf][cl * 64 + gsb * 8]);
      }
    }
    #pragma unroll
    for (int h = 0; h < 2; ++h)
      #pragma unroll
      for (int mi = 0; mi < 4; ++mi)
        #pragma unroll
        for (int ni = 0; ni < 4; ++ni)
          acc[mi][ni] = __builtin_amdgcn_mfma_f32_16x16x32_bf16(
              af[h][mi], bfr[h][ni], acc[mi][ni], 0, 0, 0);
    __syncthreads();
    if ((s & 3) == 3) EPI(s >> 2);              // tile done; overlaps next tile's in-flight stage
  }
}

// ---------------- kernel 3 (single block): loss = (Σ log(denom+0.1) - 4 Σ pair) / 2B ----------------
__global__ __launch_bounds__(1024) void tail_kernel(
    const float* __restrict__ denom, const float* __restrict__ pair,
    float* __restrict__ out)
{
  const int t = threadIdx.x;
  const int lane = t & 63, w = t >> 6;
  float c = 0.f;
  #pragma unroll
  for (int i = 0; i < 8; ++i) c += __logf(denom[t + 1024 * i] + 0.1f);
  #pragma unroll
  for (int i = 0; i < 4; ++i) c -= 4.0f * pair[t + 1024 * i];
  #pragma unroll
  for (int m = 32; m; m >>= 1) c += __shfl_xor(c, m, 64);
  __shared__ float red[16];
  if (lane == 0) red[w] = c;
  __syncthreads();
  if (t == 0) {
    float s = 0.f;
    #pragma unroll
    for (int i = 0; i < 16; ++i) s += red[i];
    out[0] = s * (1.0f / (float)TWOB);
  }
}

extern "C" void kernel_launch(void* const* d_in, const int* in_sizes, int n_in,
                              void* d_out, int out_size, void* d_ws, size_t ws_size,
                              hipStream_t stream) {
  const float* emb_i = (const float*)d_in[0];
  const float* emb_j = (const float*)d_in[1];
  const int*   tags  = (const int*)d_in[2];
  // d_in[3] = num_classes (unused)
  const int*   docs  = (const int*)d_in[4];

  char* ws = (char*)d_ws;
  bf16_t* Z     = (bf16_t*)(ws + WS_Z);
  int*    keys  = (int*)(ws + WS_KEYS);
  float*  denom = (float*)(ws + WS_DEN);
  float*  pair  = (float*)(ws + WS_PAIR);
  float*  out   = (float*)d_out;

  prep_kernel<<<B_ROWS / 2, 256, 0, stream>>>(emb_i, emb_j, tags, docs, Z, keys, denom, pair);
  const int ntiles = (TWOB / BM) * (TWOB / BM + 1) / 2;   // 2080 lower-tri tiles
  fused_kernel<<<ntiles / STRIP, 256, 0, stream>>>(Z, keys, denom);
  tail_kernel<<<1, 1024, 0, stream>>>(denom, pair, out);
}